// Round 3
// baseline (10012.151 us; speedup 1.0000x reference)
//
#include <hip/hip_runtime.h>
#include <hip/hip_bf16.h>

// Problem constants
#define SEQ   4096
#define EMB   256
#define HHID  256      // HH
#define G4    1024     // 4*HH
#define NT    9        // tags
#define TSTART 7
#define TSTOP  8
#define NEGV  (-10000.0f)
#define POISON 0xAAAAAAAAu

// Workspace byte offsets (total ~42.2 MB)
#define WS_XG_F   0u            // 4096*1024 f32 = 16 MB
#define WS_XG_B   16777216u     // 16 MB
#define WS_HF     33554432u     // 4096*256 f32 = 4 MB
#define WS_HB     37748736u     // 4 MB
#define WS_FRAMES 41943040u     // 4096*9 f32 = 147456 B

// Padded LDS index for h: groups of 32 floats padded to 36 (36 mod 32 = 4).
// The 8 cb-groups' float4 reads then start at banks 0,4,8,...,28 instead of
// all at bank 0 -> each wave's 8 distinct broadcast ds_read_b128 cover all
// 32 banks exactly once -> conflict-free (round-0 measured 2.5e7 conflict
// cycles from the unpadded layout).
#define PIDX(c) ((((c) >> 5) * 36) + ((c) & 31))

// ---------------------------------------------------------------------------
// Kernel 1: x = embed[sentence]; xg = x @ w_ih^T + b_ih + b_hh  (both dirs)
// grid (256, 2), block 256. Each block: 16 sentence positions, all 1024 gates.
// ---------------------------------------------------------------------------
__global__ __launch_bounds__(256) void xgate_kernel(
    const int* __restrict__ sentence, const float* __restrict__ embed,
    const float* __restrict__ w_ih_f, const float* __restrict__ b_ih_f,
    const float* __restrict__ b_hh_f,
    const float* __restrict__ w_ih_b, const float* __restrict__ b_ih_b,
    const float* __restrict__ b_hh_b,
    float* __restrict__ xg_f, float* __restrict__ xg_b)
{
    const int st  = blockIdx.x;          // 0..255 (16 s each)
    const int dir = blockIdx.y;
    const float* w  = dir ? w_ih_b : w_ih_f;
    const float* bi = dir ? b_ih_b : b_ih_f;
    const float* bh = dir ? b_hh_b : b_hh_f;
    float* xg = dir ? xg_b : xg_f;
    const int t = threadIdx.x;

    __shared__ float x_t[EMB][16];       // transposed x tile
    for (int sl = 0; sl < 16; ++sl) {
        int s   = st * 16 + sl;
        int tok = sentence[s];
        x_t[t][sl] = embed[(size_t)tok * EMB + t];
    }
    __syncthreads();

    float acc[4][16];
    #pragma unroll
    for (int q = 0; q < 4; ++q)
        #pragma unroll
        for (int sl = 0; sl < 16; ++sl) acc[q][sl] = 0.f;

    #pragma unroll 4
    for (int e = 0; e < EMB; ++e) {
        float w0 = w[(size_t)(t        ) * EMB + e];
        float w1 = w[(size_t)(t + 256  ) * EMB + e];
        float w2 = w[(size_t)(t + 512  ) * EMB + e];
        float w3 = w[(size_t)(t + 768  ) * EMB + e];
        #pragma unroll
        for (int sl = 0; sl < 16; ++sl) {
            float xv = x_t[e][sl];
            acc[0][sl] += w0 * xv;
            acc[1][sl] += w1 * xv;
            acc[2][sl] += w2 * xv;
            acc[3][sl] += w3 * xv;
        }
    }

    #pragma unroll
    for (int q = 0; q < 4; ++q) {
        int g = t + 256 * q;
        float bb = bi[g] + bh[g];
        for (int sl = 0; sl < 16; ++sl) {
            xg[(size_t)(st * 16 + sl) * G4 + g] = acc[q][sl] + bb;
        }
    }
}

// ---------------------------------------------------------------------------
// Kernel 2: bidirectional LSTM recurrence. 16 blocks x 256 threads.
// blocks 0..7 = forward slices, 8..15 = backward slices.
//
// EXACT round-0 exchange structure (per-thread 4B relaxed agent-scope
// atomics + own-slice LDS shortcut — the only structure proven to pass),
// with two semantics-preserving changes:
//   (a) s_sleep(1) backoff in the poison-poll loop. Round-0 measured 52 GB
//       of poll fetch traffic at 7.5 TB/s — contention roughly doubled the
//       produce->observe round trip. Sleeping ~64cy between sweeps cuts the
//       sweep rate ~20-40x; the first probe is sleep-free so the
//       data-already-there fast path pays nothing.
//   (b) PIDX-padded LDS h buffer: kills the measured 2.5e7 8-way read
//       conflict cycles on the float4 h reads.
//
// Thread t = (unit rb = t>>3 within slice, col-block cb = t&7).
// Each thread: partials of ALL 4 gates of unit (slice*32+rb) over 32 h-cols.
// Weights (128 fp32/thread) held in AGPRs via explicit v_accvgpr_write/read.
// 8-lane shfl_xor reduce -> lane cb==0 owns all 4 gates of its unit, does
// activations + c-state + h store. ONE __syncthreads per step.
// ---------------------------------------------------------------------------
__global__ __launch_bounds__(256, 1) void lstm_kernel(
    const float* __restrict__ xg_f, const float* __restrict__ xg_b,
    const float* __restrict__ w_hh_f, const float* __restrict__ w_hh_b,
    const float* __restrict__ h0, const float* __restrict__ c0,
    float* __restrict__ hf, float* __restrict__ hb)
{
    const int bx    = blockIdx.x;
    const int dir   = bx >> 3;
    const int slice = bx & 7;
    const int t     = threadIdx.x;
    const int cb    = t & 7;          // col block: h cols cb*32 .. cb*32+31
    const int rb    = t >> 3;         // unit within slice (0..31)
    const int unit  = slice * 32 + rb;

    const float* xg   = dir ? xg_b  : xg_f;
    const float* w_hh = dir ? w_hh_b : w_hh_f;
    float* hout = dir ? hb : hf;

    __shared__ float buf[2][288];     // h ping-pong, 36-float padded groups

    // --- weights into AGPRs: wa[q*32+j] = W[q*256+unit][cb*32+j] ---
    float wa[128];
    #pragma unroll
    for (int q = 0; q < 4; ++q) {
        #pragma unroll
        for (int j = 0; j < 32; ++j) {
            float tmp = w_hh[(size_t)(q * HHID + unit) * HHID + cb * 32 + j];
            asm volatile("v_accvgpr_write_b32 %0, %1"
                         : "=a"(wa[q * 32 + j]) : "v"(tmp));
        }
    }

    float c_reg = 0.f;
    if (cb == 0) c_reg = c0[dir * HHID + unit];

    const bool own = (t >= slice * 32) && (t < slice * 32 + 32);

    for (int n = 0; n < SEQ; ++n) {
        const int s = dir ? (SEQ - 1 - n) : n;

        // Prefetch xg (independent of h; issues before the poll)
        float xg0 = 0.f, xg1 = 0.f, xg2 = 0.f, xg3 = 0.f;
        if (cb == 0) {
            const float* xb = xg + (size_t)s * G4 + unit;
            xg0 = xb[0];
            xg1 = xb[HHID];
            xg2 = xb[2 * HHID];
            xg3 = xb[3 * HHID];
        }

        // Obtain h_prev word t into LDS (own 32 words arrive via local path)
        if (n == 0) {
            buf[0][PIDX(t)] = h0[dir * HHID + t];
        } else if (!own) {
            const int sp = dir ? (s + 1) : (s - 1);
            const unsigned int* src =
                (const unsigned int*)(hout + (size_t)sp * HHID) + t;
            unsigned v = __hip_atomic_load(src, __ATOMIC_RELAXED,
                                           __HIP_MEMORY_SCOPE_AGENT);
            while (v == POISON) {
                __builtin_amdgcn_s_sleep(1);   // ~64cy backoff between sweeps
                v = __hip_atomic_load(src, __ATOMIC_RELAXED,
                                      __HIP_MEMORY_SCOPE_AGENT);
            }
            buf[n & 1][PIDX(t)] = __uint_as_float(v);
        }
        __syncthreads();

        // 32-col partial dot for 4 gates (weights from AGPRs, h from LDS)
        float a0 = 0.f, a1 = 0.f, a2 = 0.f, a3 = 0.f;
        const float4* h4 = (const float4*)(&buf[n & 1][cb * 36]);
        #pragma unroll
        for (int j4 = 0; j4 < 8; ++j4) {
            float4 hv = h4[j4];
            #pragma unroll
            for (int k = 0; k < 4; ++k) {
                float hk = (k == 0) ? hv.x : (k == 1) ? hv.y
                         : (k == 2) ? hv.z : hv.w;
                float w0, w1, w2, w3;
                asm volatile("v_accvgpr_read_b32 %0, %1"
                             : "=v"(w0) : "a"(wa[0 * 32 + j4 * 4 + k]));
                asm volatile("v_accvgpr_read_b32 %0, %1"
                             : "=v"(w1) : "a"(wa[1 * 32 + j4 * 4 + k]));
                asm volatile("v_accvgpr_read_b32 %0, %1"
                             : "=v"(w2) : "a"(wa[2 * 32 + j4 * 4 + k]));
                asm volatile("v_accvgpr_read_b32 %0, %1"
                             : "=v"(w3) : "a"(wa[3 * 32 + j4 * 4 + k]));
                a0 += w0 * hk;
                a1 += w1 * hk;
                a2 += w2 * hk;
                a3 += w3 * hk;
            }
        }

        // 8-lane butterfly reduce across col blocks (lanes cb = t&7)
        #pragma unroll
        for (int m = 1; m <= 4; m <<= 1) {
            a0 += __shfl_xor(a0, m);
            a1 += __shfl_xor(a1, m);
            a2 += __shfl_xor(a2, m);
            a3 += __shfl_xor(a3, m);
        }

        // Lane cb==0: activations, state, h store (global + local shortcut)
        if (cb == 0) {
            float gi = a0 + xg0;
            float gf = a1 + xg1;
            float gg = a2 + xg2;
            float go = a3 + xg3;
            float iv = 1.f / (1.f + __expf(-gi));
            float fv = 1.f / (1.f + __expf(-gf));
            float gv = 1.f - 2.f / (__expf(2.f * gg) + 1.f);   // tanh
            float ov = 1.f / (1.f + __expf(-go));
            float c  = fv * c_reg + iv * gv;
            c_reg = c;
            float h  = ov * (1.f - 2.f / (__expf(2.f * c) + 1.f));
            unsigned int* dst =
                (unsigned int*)(hout + (size_t)s * HHID) + unit;
            __hip_atomic_store(dst, __float_as_uint(h), __ATOMIC_RELAXED,
                               __HIP_MEMORY_SCOPE_AGENT);
            buf[(n + 1) & 1][PIDX(unit)] = h;   // local shortcut, next step
        }
        // No second barrier: writes above target buf[(n+1)&1]; concurrent
        // readers of this step use buf[n&1]. The next iteration's single
        // barrier orders buf[(n+1)&1] for its dot.
    }
}

// ---------------------------------------------------------------------------
// Kernel 3: frames = [hf|hb] @ W_out^T + b_out      (4096 x 9)
// ---------------------------------------------------------------------------
__global__ __launch_bounds__(256) void frames_kernel(
    const float* __restrict__ hf, const float* __restrict__ hb,
    const float* __restrict__ W_out, const float* __restrict__ b_out,
    float* __restrict__ frames)
{
    int o = blockIdx.x * 256 + threadIdx.x;
    if (o >= SEQ * NT) return;
    int s = o / NT;
    int j = o - s * NT;
    const float4* a0 = (const float4*)(hf + (size_t)s * HHID);
    const float4* a1 = (const float4*)(hb + (size_t)s * HHID);
    const float4* w0 = (const float4*)(W_out + (size_t)j * 512);
    const float4* w1 = w0 + 64;
    float acc = 0.f;
    #pragma unroll 8
    for (int i = 0; i < 64; ++i) {
        float4 a = a0[i], b = w0[i];
        acc += a.x * b.x + a.y * b.y + a.z * b.z + a.w * b.w;
        float4 c = a1[i], d = w1[i];
        acc += c.x * d.x + c.y * d.y + c.z * d.z + c.w * d.w;
    }
    frames[o] = acc + b_out[j];
}

// ---------------------------------------------------------------------------
// Kernel 4: fused CRF forward + backtrack. ONE wave (64 threads), no inner-
// loop barriers. Per-lane alpha (lanes 0..8 meaningful), cross-lane reads via
// __shfl executed by ALL lanes. Backpointers in LDS; t0 backtracks at the
// end and writes tags directly to dout. Score -> dout[0].
// ---------------------------------------------------------------------------
__global__ __launch_bounds__(64) void crf_kernel(
    const float* __restrict__ frames, const float* __restrict__ trans,
    float* __restrict__ dout)
{
    __shared__ float fr[512 * NT];                 // 18432 B chunk of frames
    __shared__ unsigned char bpl[SEQ * NT];        // 36864 B backpointers
    const int t = threadIdx.x;
    const int tc = (t < NT) ? t : 0;               // clamped lane for fr reads

    float trow[NT];
    #pragma unroll
    for (int i = 0; i < NT; ++i) trow[i] = 0.f;
    if (t < NT) {
        #pragma unroll
        for (int i = 0; i < NT; ++i) trow[i] = trans[i * NT + t];
    }
    float alpha = (t == TSTART) ? 0.f : NEGV;      // lane t holds alpha[t]

    for (int chunk = 0; chunk < 8; ++chunk) {
        for (int idx = t; idx < 512 * NT; idx += 64)
            fr[idx] = frames[chunk * 512 * NT + idx];
        __syncthreads();   // single wave: cheap

        for (int sl = 0; sl < 512; ++sl) {
            const int s = chunk * 512 + sl;
            float v[NT];
            #pragma unroll
            for (int i = 0; i < NT; ++i)
                v[i] = __shfl(alpha, i) + trow[i];     // all lanes active
            float mx = v[0];
            int   am = 0;
            #pragma unroll
            for (int i = 1; i < NT; ++i)
                if (v[i] > mx) { mx = v[i]; am = i; }
            float sum = 0.f;
            #pragma unroll
            for (int i = 0; i < NT; ++i) sum += __expf(v[i] - mx);
            float anew = fr[sl * NT + tc] + mx + __logf(sum);
            if (t < NT) {
                bpl[s * NT + t] = (unsigned char)am;
                alpha = anew;
            }
        }
        __syncthreads();
    }

    // final: fin[j] = alpha[j] + trans[j, STOP]; gather with ALL lanes active
    float fin = NEGV;
    if (t < NT) fin = alpha + trans[t * NT + TSTOP];
    float f[NT];
    #pragma unroll
    for (int j = 0; j < NT; ++j) f[j] = __shfl(fin, j);  // all lanes active

    if (t == 0) {
        float mx = f[0];
        int best = 0;
        #pragma unroll
        for (int j = 1; j < NT; ++j)
            if (f[j] > mx) { mx = f[j]; best = j; }
        float sum = 0.f;
        #pragma unroll
        for (int j = 0; j < NT; ++j) sum += __expf(f[j] - mx);
        dout[0] = mx + __logf(sum);

        // backtrack entirely from LDS, stream tags straight to dout
        int cur = best;
        dout[1 + SEQ - 1] = (float)cur;
        for (int s = SEQ - 2; s >= 0; --s) {
            cur = bpl[(s + 1) * NT + cur];
            dout[1 + s] = (float)cur;
        }
    }
}

// ---------------------------------------------------------------------------
extern "C" void kernel_launch(void* const* d_in, const int* in_sizes, int n_in,
                              void* d_out, int out_size, void* d_ws, size_t ws_size,
                              hipStream_t stream)
{
    const int*   sentence = (const int*)  d_in[0];
    const float* embed    = (const float*)d_in[1];
    const float* w_ih_f   = (const float*)d_in[2];
    const float* w_hh_f   = (const float*)d_in[3];
    const float* b_ih_f   = (const float*)d_in[4];
    const float* b_hh_f   = (const float*)d_in[5];
    const float* w_ih_b   = (const float*)d_in[6];
    const float* w_hh_b   = (const float*)d_in[7];
    const float* b_ih_b   = (const float*)d_in[8];
    const float* b_hh_b   = (const float*)d_in[9];
    const float* h0       = (const float*)d_in[10];
    const float* c0       = (const float*)d_in[11];
    const float* W_out    = (const float*)d_in[12];
    const float* b_out    = (const float*)d_in[13];
    const float* trans    = (const float*)d_in[14];

    float* out = (float*)d_out;
    char*  ws  = (char*)d_ws;

    float* xg_f   = (float*)(ws + WS_XG_F);
    float* xg_b   = (float*)(ws + WS_XG_B);
    float* hf     = (float*)(ws + WS_HF);
    float* hb     = (float*)(ws + WS_HB);
    float* frames = (float*)(ws + WS_FRAMES);

    // Ensure hf/hb are poison (the "not yet written" sentinel) regardless of
    // harness state. hf and hb are contiguous: one 8 MB async memset.
    hipMemsetAsync(hf, 0xAA, 2u * SEQ * HHID * sizeof(float), stream);

    xgate_kernel<<<dim3(256, 2), 256, 0, stream>>>(
        sentence, embed, w_ih_f, b_ih_f, b_hh_f, w_ih_b, b_ih_b, b_hh_b,
        xg_f, xg_b);

    lstm_kernel<<<16, 256, 0, stream>>>(
        xg_f, xg_b, w_hh_f, w_hh_b, h0, c0, hf, hb);

    frames_kernel<<<(SEQ * NT + 255) / 256, 256, 0, stream>>>(
        hf, hb, W_out, b_out, frames);

    crf_kernel<<<1, 64, 0, stream>>>(frames, trans, out);
}

// Round 4
// 9913.854 us; speedup vs baseline: 1.0099x; 1.0099x over previous
//
#include <hip/hip_runtime.h>
#include <hip/hip_bf16.h>

// Problem constants
#define SEQ   4096
#define EMB   256
#define HHID  256      // HH
#define G4    1024     // 4*HH
#define NT    9        // tags
#define TSTART 7
#define TSTOP  8
#define NEGV  (-10000.0f)
#define POISON 0xAAAAAAAAu

// Workspace byte offsets (total ~42.2 MB)
#define WS_XG_F   0u            // 4096*1024 f32 = 16 MB
#define WS_XG_B   16777216u     // 16 MB
#define WS_HF     33554432u     // 4096*256 f32 = 4 MB
#define WS_HB     37748736u     // 4 MB
#define WS_FRAMES 41943040u     // 4096*9 f32 = 147456 B

// Padded LDS index for h: groups of 32 floats padded to 36 (36 mod 32 = 4).
// The 8 cb-groups' float4 reads start at banks 0,4,8,...,28 -> conflict-free
// (round-3 verified: SQ_LDS_BANK_CONFLICT 2.5e7 -> 0).
#define PIDX(c) ((((c) >> 5) * 36) + ((c) & 31))

// ---------------------------------------------------------------------------
// Kernel 1: x = embed[sentence]; xg = x @ w_ih^T + b_ih + b_hh  (both dirs)
// grid (256, 2), block 256. Each block: 16 sentence positions, all 1024 gates.
// xg layout is GATE-INTERLEAVED: xg[s][unit*4 + q] so the LSTM consumer
// reads one float4 per unit instead of 4 dwords at 1KB stride.
// ---------------------------------------------------------------------------
__global__ __launch_bounds__(256) void xgate_kernel(
    const int* __restrict__ sentence, const float* __restrict__ embed,
    const float* __restrict__ w_ih_f, const float* __restrict__ b_ih_f,
    const float* __restrict__ b_hh_f,
    const float* __restrict__ w_ih_b, const float* __restrict__ b_ih_b,
    const float* __restrict__ b_hh_b,
    float* __restrict__ xg_f, float* __restrict__ xg_b)
{
    const int st  = blockIdx.x;          // 0..255 (16 s each)
    const int dir = blockIdx.y;
    const float* w  = dir ? w_ih_b : w_ih_f;
    const float* bi = dir ? b_ih_b : b_ih_f;
    const float* bh = dir ? b_hh_b : b_hh_f;
    float* xg = dir ? xg_b : xg_f;
    const int t = threadIdx.x;

    __shared__ float x_t[EMB][16];       // transposed x tile
    for (int sl = 0; sl < 16; ++sl) {
        int s   = st * 16 + sl;
        int tok = sentence[s];
        x_t[t][sl] = embed[(size_t)tok * EMB + t];
    }
    __syncthreads();

    float acc[4][16];
    #pragma unroll
    for (int q = 0; q < 4; ++q)
        #pragma unroll
        for (int sl = 0; sl < 16; ++sl) acc[q][sl] = 0.f;

    // Per-thread rows t, t+256, t+512, t+768; float4 loads along e (each
    // lane streams its rows linearly -> lines fully consumed via L1/L2).
    const float4* wr0 = (const float4*)(w + (size_t)(t      ) * EMB);
    const float4* wr1 = (const float4*)(w + (size_t)(t + 256) * EMB);
    const float4* wr2 = (const float4*)(w + (size_t)(t + 512) * EMB);
    const float4* wr3 = (const float4*)(w + (size_t)(t + 768) * EMB);
    #pragma unroll 2
    for (int e4 = 0; e4 < EMB / 4; ++e4) {
        float4 w0 = wr0[e4], w1 = wr1[e4], w2 = wr2[e4], w3 = wr3[e4];
        #pragma unroll
        for (int k = 0; k < 4; ++k) {
            float f0 = (k == 0) ? w0.x : (k == 1) ? w0.y : (k == 2) ? w0.z : w0.w;
            float f1 = (k == 0) ? w1.x : (k == 1) ? w1.y : (k == 2) ? w1.z : w1.w;
            float f2 = (k == 0) ? w2.x : (k == 1) ? w2.y : (k == 2) ? w2.z : w2.w;
            float f3 = (k == 0) ? w3.x : (k == 1) ? w3.y : (k == 2) ? w3.z : w3.w;
            int e = e4 * 4 + k;
            #pragma unroll
            for (int sl = 0; sl < 16; ++sl) {
                float xv = x_t[e][sl];
                acc[0][sl] += f0 * xv;
                acc[1][sl] += f1 * xv;
                acc[2][sl] += f2 * xv;
                acc[3][sl] += f3 * xv;
            }
        }
    }

    float bb0 = bi[t      ] + bh[t      ];
    float bb1 = bi[t + 256] + bh[t + 256];
    float bb2 = bi[t + 512] + bh[t + 512];
    float bb3 = bi[t + 768] + bh[t + 768];
    for (int sl = 0; sl < 16; ++sl) {
        float4 val = make_float4(acc[0][sl] + bb0, acc[1][sl] + bb1,
                                 acc[2][sl] + bb2, acc[3][sl] + bb3);
        ((float4*)(xg + (size_t)(st * 16 + sl) * G4))[t] = val;
    }
}

// ---------------------------------------------------------------------------
// Kernel 2: bidirectional LSTM recurrence. 16 blocks x 256 threads.
// blocks 0..7 = forward slices, 8..15 = backward slices.
//
// Round-0/3 exchange structure (per-thread 4B relaxed agent-scope atomics +
// own-slice LDS shortcut — proven correct), with a latency-targeted poll:
//
//   STAGGERED QUAD-SLOT POLL. Round-3 showed the chain is pure latency
//   (hbm 7.4 GB/s = 0.09% peak; bank conflicts 0 with no time change).
//   Per-step ~4890cy ≈ T_vis(~900) + detect(phase≈L + L, L≈900) +
//   compute(~800) + barrier(~250). The only software-addressable term is
//   the sampling phase: keep 4 relaxed loads in flight, initial issues
//   staggered by s_sleep(2) (~128cy), so the word is sampled every ~L/4
//   instead of every ~L. Loop still exits only on non-poison: no hang risk.
//
// Thread t = (unit rb = t>>3 within slice, col-block cb = t&7).
// Each thread: partials of ALL 4 gates of unit (slice*32+rb) over 32 h-cols.
// Weights (128 fp32/thread) held in AGPRs via explicit v_accvgpr_write/read.
// 8-lane shfl_xor reduce -> lane cb==0 owns all 4 gates of its unit, does
// activations + c-state + h store. ONE __syncthreads per step.
// ---------------------------------------------------------------------------
__global__ __launch_bounds__(256, 1) void lstm_kernel(
    const float* __restrict__ xg_f, const float* __restrict__ xg_b,
    const float* __restrict__ w_hh_f, const float* __restrict__ w_hh_b,
    const float* __restrict__ h0, const float* __restrict__ c0,
    float* __restrict__ hf, float* __restrict__ hb)
{
    const int bx    = blockIdx.x;
    const int dir   = bx >> 3;
    const int slice = bx & 7;
    const int t     = threadIdx.x;
    const int cb    = t & 7;          // col block: h cols cb*32 .. cb*32+31
    const int rb    = t >> 3;         // unit within slice (0..31)
    const int unit  = slice * 32 + rb;

    const float* xg   = dir ? xg_b  : xg_f;
    const float* w_hh = dir ? w_hh_b : w_hh_f;
    float* hout = dir ? hb : hf;

    __shared__ float buf[2][288];     // h ping-pong, 36-float padded groups

    // --- weights into AGPRs: wa[q*32+j] = W[q*256+unit][cb*32+j] ---
    float wa[128];
    #pragma unroll
    for (int q = 0; q < 4; ++q) {
        #pragma unroll
        for (int j = 0; j < 32; ++j) {
            float tmp = w_hh[(size_t)(q * HHID + unit) * HHID + cb * 32 + j];
            asm volatile("v_accvgpr_write_b32 %0, %1"
                         : "=a"(wa[q * 32 + j]) : "v"(tmp));
        }
    }

    float c_reg = 0.f;
    if (cb == 0) c_reg = c0[dir * HHID + unit];

    const bool own = (t >= slice * 32) && (t < slice * 32 + 32);

    for (int n = 0; n < SEQ; ++n) {
        const int s = dir ? (SEQ - 1 - n) : n;

        // Prefetch xg (independent of h; issues before the poll).
        // Gate-interleaved layout: one float4 at xg[s][4*unit].
        float4 xgv = make_float4(0.f, 0.f, 0.f, 0.f);
        if (cb == 0) {
            xgv = *(const float4*)(xg + (size_t)s * G4 + 4u * unit);
        }

        // Obtain h_prev word t into LDS (own 32 words arrive via local path)
        if (n == 0) {
            buf[0][PIDX(t)] = h0[dir * HHID + t];
        } else if (!own) {
            const int sp = dir ? (s + 1) : (s - 1);
            const unsigned int* src =
                (const unsigned int*)(hout + (size_t)sp * HHID) + t;
            unsigned v = __hip_atomic_load(src, __ATOMIC_RELAXED,
                                           __HIP_MEMORY_SCOPE_AGENT);
            if (v == POISON) {
                // staggered quad-slot poll: 4 samples in flight ~L/4 apart
                unsigned q0, q1, q2, q3;
                q0 = __hip_atomic_load(src, __ATOMIC_RELAXED,
                                       __HIP_MEMORY_SCOPE_AGENT);
                __builtin_amdgcn_s_sleep(2);
                q1 = __hip_atomic_load(src, __ATOMIC_RELAXED,
                                       __HIP_MEMORY_SCOPE_AGENT);
                __builtin_amdgcn_s_sleep(2);
                q2 = __hip_atomic_load(src, __ATOMIC_RELAXED,
                                       __HIP_MEMORY_SCOPE_AGENT);
                __builtin_amdgcn_s_sleep(2);
                q3 = __hip_atomic_load(src, __ATOMIC_RELAXED,
                                       __HIP_MEMORY_SCOPE_AGENT);
                for (;;) {
                    if (q0 != POISON) { v = q0; break; }
                    q0 = __hip_atomic_load(src, __ATOMIC_RELAXED,
                                           __HIP_MEMORY_SCOPE_AGENT);
                    if (q1 != POISON) { v = q1; break; }
                    q1 = __hip_atomic_load(src, __ATOMIC_RELAXED,
                                           __HIP_MEMORY_SCOPE_AGENT);
                    if (q2 != POISON) { v = q2; break; }
                    q2 = __hip_atomic_load(src, __ATOMIC_RELAXED,
                                           __HIP_MEMORY_SCOPE_AGENT);
                    if (q3 != POISON) { v = q3; break; }
                    q3 = __hip_atomic_load(src, __ATOMIC_RELAXED,
                                           __HIP_MEMORY_SCOPE_AGENT);
                }
            }
            buf[n & 1][PIDX(t)] = __uint_as_float(v);
        }
        __syncthreads();

        // 32-col partial dot for 4 gates (weights from AGPRs, h from LDS)
        float a0 = 0.f, a1 = 0.f, a2 = 0.f, a3 = 0.f;
        const float4* h4 = (const float4*)(&buf[n & 1][cb * 36]);
        #pragma unroll
        for (int j4 = 0; j4 < 8; ++j4) {
            float4 hv = h4[j4];
            #pragma unroll
            for (int k = 0; k < 4; ++k) {
                float hk = (k == 0) ? hv.x : (k == 1) ? hv.y
                         : (k == 2) ? hv.z : hv.w;
                float w0, w1, w2, w3;
                asm volatile("v_accvgpr_read_b32 %0, %1"
                             : "=v"(w0) : "a"(wa[0 * 32 + j4 * 4 + k]));
                asm volatile("v_accvgpr_read_b32 %0, %1"
                             : "=v"(w1) : "a"(wa[1 * 32 + j4 * 4 + k]));
                asm volatile("v_accvgpr_read_b32 %0, %1"
                             : "=v"(w2) : "a"(wa[2 * 32 + j4 * 4 + k]));
                asm volatile("v_accvgpr_read_b32 %0, %1"
                             : "=v"(w3) : "a"(wa[3 * 32 + j4 * 4 + k]));
                a0 += w0 * hk;
                a1 += w1 * hk;
                a2 += w2 * hk;
                a3 += w3 * hk;
            }
        }

        // 8-lane butterfly reduce across col blocks (lanes cb = t&7)
        #pragma unroll
        for (int m = 1; m <= 4; m <<= 1) {
            a0 += __shfl_xor(a0, m);
            a1 += __shfl_xor(a1, m);
            a2 += __shfl_xor(a2, m);
            a3 += __shfl_xor(a3, m);
        }

        // Lane cb==0: activations, state, h store (global + local shortcut)
        if (cb == 0) {
            float gi = a0 + xgv.x;
            float gf = a1 + xgv.y;
            float gg = a2 + xgv.z;
            float go = a3 + xgv.w;
            float iv = 1.f / (1.f + __expf(-gi));
            float fv = 1.f / (1.f + __expf(-gf));
            float gv = 1.f - 2.f / (__expf(2.f * gg) + 1.f);   // tanh
            float ov = 1.f / (1.f + __expf(-go));
            float c  = fv * c_reg + iv * gv;
            c_reg = c;
            float h  = ov * (1.f - 2.f / (__expf(2.f * c) + 1.f));
            unsigned int* dst =
                (unsigned int*)(hout + (size_t)s * HHID) + unit;
            __hip_atomic_store(dst, __float_as_uint(h), __ATOMIC_RELAXED,
                               __HIP_MEMORY_SCOPE_AGENT);
            buf[(n + 1) & 1][PIDX(unit)] = h;   // local shortcut, next step
        }
        // No second barrier: writes above target buf[(n+1)&1]; concurrent
        // readers of this step use buf[n&1]. The next iteration's single
        // barrier orders buf[(n+1)&1] for its dot.
    }
}

// ---------------------------------------------------------------------------
// Kernel 3: frames = [hf|hb] @ W_out^T + b_out      (4096 x 9)
// ---------------------------------------------------------------------------
__global__ __launch_bounds__(256) void frames_kernel(
    const float* __restrict__ hf, const float* __restrict__ hb,
    const float* __restrict__ W_out, const float* __restrict__ b_out,
    float* __restrict__ frames)
{
    int o = blockIdx.x * 256 + threadIdx.x;
    if (o >= SEQ * NT) return;
    int s = o / NT;
    int j = o - s * NT;
    const float4* a0 = (const float4*)(hf + (size_t)s * HHID);
    const float4* a1 = (const float4*)(hb + (size_t)s * HHID);
    const float4* w0 = (const float4*)(W_out + (size_t)j * 512);
    const float4* w1 = w0 + 64;
    float acc = 0.f;
    #pragma unroll 8
    for (int i = 0; i < 64; ++i) {
        float4 a = a0[i], b = w0[i];
        acc += a.x * b.x + a.y * b.y + a.z * b.z + a.w * b.w;
        float4 c = a1[i], d = w1[i];
        acc += c.x * d.x + c.y * d.y + c.z * d.z + c.w * d.w;
    }
    frames[o] = acc + b_out[j];
}

// ---------------------------------------------------------------------------
// Kernel 4: fused CRF forward + backtrack. ONE wave (64 threads), no inner-
// loop barriers. Per-lane alpha (lanes 0..8 meaningful), cross-lane reads via
// __shfl executed by ALL lanes. Backpointers in LDS; t0 backtracks at the
// end and writes tags directly to dout. Score -> dout[0].
// ---------------------------------------------------------------------------
__global__ __launch_bounds__(64) void crf_kernel(
    const float* __restrict__ frames, const float* __restrict__ trans,
    float* __restrict__ dout)
{
    __shared__ float fr[512 * NT];                 // 18432 B chunk of frames
    __shared__ unsigned char bpl[SEQ * NT];        // 36864 B backpointers
    const int t = threadIdx.x;
    const int tc = (t < NT) ? t : 0;               // clamped lane for fr reads

    float trow[NT];
    #pragma unroll
    for (int i = 0; i < NT; ++i) trow[i] = 0.f;
    if (t < NT) {
        #pragma unroll
        for (int i = 0; i < NT; ++i) trow[i] = trans[i * NT + t];
    }
    float alpha = (t == TSTART) ? 0.f : NEGV;      // lane t holds alpha[t]

    for (int chunk = 0; chunk < 8; ++chunk) {
        for (int idx = t; idx < 512 * NT; idx += 64)
            fr[idx] = frames[chunk * 512 * NT + idx];
        __syncthreads();   // single wave: cheap

        for (int sl = 0; sl < 512; ++sl) {
            const int s = chunk * 512 + sl;
            float v[NT];
            #pragma unroll
            for (int i = 0; i < NT; ++i)
                v[i] = __shfl(alpha, i) + trow[i];     // all lanes active
            float mx = v[0];
            int   am = 0;
            #pragma unroll
            for (int i = 1; i < NT; ++i)
                if (v[i] > mx) { mx = v[i]; am = i; }
            float sum = 0.f;
            #pragma unroll
            for (int i = 0; i < NT; ++i) sum += __expf(v[i] - mx);
            float anew = fr[sl * NT + tc] + mx + __logf(sum);
            if (t < NT) {
                bpl[s * NT + t] = (unsigned char)am;
                alpha = anew;
            }
        }
        __syncthreads();
    }

    // final: fin[j] = alpha[j] + trans[j, STOP]; gather with ALL lanes active
    float fin = NEGV;
    if (t < NT) fin = alpha + trans[t * NT + TSTOP];
    float f[NT];
    #pragma unroll
    for (int j = 0; j < NT; ++j) f[j] = __shfl(fin, j);  // all lanes active

    if (t == 0) {
        float mx = f[0];
        int best = 0;
        #pragma unroll
        for (int j = 1; j < NT; ++j)
            if (f[j] > mx) { mx = f[j]; best = j; }
        float sum = 0.f;
        #pragma unroll
        for (int j = 0; j < NT; ++j) sum += __expf(f[j] - mx);
        dout[0] = mx + __logf(sum);

        // backtrack entirely from LDS, stream tags straight to dout
        int cur = best;
        dout[1 + SEQ - 1] = (float)cur;
        for (int s = SEQ - 2; s >= 0; --s) {
            cur = bpl[(s + 1) * NT + cur];
            dout[1 + s] = (float)cur;
        }
    }
}

// ---------------------------------------------------------------------------
extern "C" void kernel_launch(void* const* d_in, const int* in_sizes, int n_in,
                              void* d_out, int out_size, void* d_ws, size_t ws_size,
                              hipStream_t stream)
{
    const int*   sentence = (const int*)  d_in[0];
    const float* embed    = (const float*)d_in[1];
    const float* w_ih_f   = (const float*)d_in[2];
    const float* w_hh_f   = (const float*)d_in[3];
    const float* b_ih_f   = (const float*)d_in[4];
    const float* b_hh_f   = (const float*)d_in[5];
    const float* w_ih_b   = (const float*)d_in[6];
    const float* w_hh_b   = (const float*)d_in[7];
    const float* b_ih_b   = (const float*)d_in[8];
    const float* b_hh_b   = (const float*)d_in[9];
    const float* h0       = (const float*)d_in[10];
    const float* c0       = (const float*)d_in[11];
    const float* W_out    = (const float*)d_in[12];
    const float* b_out    = (const float*)d_in[13];
    const float* trans    = (const float*)d_in[14];

    float* out = (float*)d_out;
    char*  ws  = (char*)d_ws;

    float* xg_f   = (float*)(ws + WS_XG_F);
    float* xg_b   = (float*)(ws + WS_XG_B);
    float* hf     = (float*)(ws + WS_HF);
    float* hb     = (float*)(ws + WS_HB);
    float* frames = (float*)(ws + WS_FRAMES);

    // Ensure hf/hb are poison (the "not yet written" sentinel) regardless of
    // harness state. hf and hb are contiguous: one 8 MB async memset.
    hipMemsetAsync(hf, 0xAA, 2u * SEQ * HHID * sizeof(float), stream);

    xgate_kernel<<<dim3(256, 2), 256, 0, stream>>>(
        sentence, embed, w_ih_f, b_ih_f, b_hh_f, w_ih_b, b_ih_b, b_hh_b,
        xg_f, xg_b);

    lstm_kernel<<<16, 256, 0, stream>>>(
        xg_f, xg_b, w_hh_f, w_hh_b, h0, c0, hf, hb);

    frames_kernel<<<(SEQ * NT + 255) / 256, 256, 0, stream>>>(
        hf, hb, W_out, b_out, frames);

    crf_kernel<<<1, 64, 0, stream>>>(frames, trans, out);
}